// Round 1
// baseline (697.849 us; speedup 1.0000x reference)
//
#include <hip/hip_runtime.h>

#define L_DIM 4096
#define H_DIM 16
#define E_DIM 64
#define BH 128
#define ROWSTRIDE 1024  // H_DIM*E_DIM floats between consecutive l

#define P1_CHUNK 512
#define P2_CHUNK 512

__device__ __forceinline__ float inv_softplus_temp(const float* delta1) {
  // temp = softplus(delta1); return 1/temp
  return 1.0f / log1pf(__expf(delta1[0]));
}

__device__ __forceinline__ void lds_fence() {
  // Intra-wave LDS RAW visibility: a wave's DS ops complete in order; waiting
  // lgkmcnt(0) guarantees all 64 lanes' preceding ds_writes are visible to
  // this wave's subsequent ds_reads. No __syncthreads needed (wave-private LDS).
  asm volatile("s_waitcnt lgkmcnt(0)" ::: "memory");
}

// Phase 1: per (b,h) accumulate KV[d][e] = sum_l ktil[l][d]*v[l][e], ksum[d].
// Each wave owns 128 consecutive rows and a private LDS tile -> no barriers
// in the main loop. Cross-wave merge once at block end.
__global__ __launch_bounds__(256, 4) void p1_kv(
    const float* __restrict__ Kp, const float* __restrict__ Vp,
    const float* __restrict__ delta1,
    float* __restrict__ ws_kv, float* __restrict__ ws_ksum) {
  const int t = threadIdx.x;
  const int bh = blockIdx.y;
  const int b = bh >> 4, h = bh & 15;
  const int lane = t & 63;
  const int w = t >> 6;
  const float inv_temp = inv_softplus_temp(delta1);
  const size_t base = ((size_t)b * L_DIM * H_DIM + h) * E_DIM;
  const int l0 = blockIdx.x * P1_CHUNK + w * (P1_CHUNK / 4);

  const int rsub = lane >> 4;           // row within 4-row group
  const int equad = (lane & 15) << 2;   // load/store column quad
  const int d0 = (lane >> 3) << 3;      // 8-wide d-tile base (0..56)
  const int e0 = (lane & 7) << 3;       // 8-wide e-tile base (0..56)

  __shared__ float sk[4][4][64];  // [wave][row][col] -- wave-private
  __shared__ float sv[4][4][64];
  __shared__ float red[4096];     // cross-wave KV reduction buffer

  float acc[8][8];
#pragma unroll
  for (int i = 0; i < 8; ++i)
#pragma unroll
    for (int j = 0; j < 8; ++j) acc[i][j] = 0.f;
  float ksk[4] = {0.f, 0.f, 0.f, 0.f};

  const int NIT = (P1_CHUNK / 4) / 4;  // 32 iterations of 4 rows per wave
  const float* kp = Kp + base + (size_t)(l0 + rsub) * ROWSTRIDE + equad;
  const float* vp = Vp + base + (size_t)(l0 + rsub) * ROWSTRIDE + equad;

  float4 k4 = *(const float4*)kp;
  float4 v4 = *(const float4*)vp;

  for (int it = 0; it < NIT; ++it) {
    // prefetch next 4-row group (clamped; last iter re-reads = L1 hit)
    const int pit = (it + 1 < NIT) ? it + 1 : it;
    const float4 nk4 = *(const float4*)(kp + (size_t)pit * (4 * ROWSTRIDE));
    const float4 nv4 = *(const float4*)(vp + (size_t)pit * (4 * ROWSTRIDE));

    float ex = __expf((k4.x < 0.f ? -20.f : k4.x) * inv_temp);
    float ey = __expf((k4.y < 0.f ? -20.f : k4.y) * inv_temp);
    float ez = __expf((k4.z < 0.f ? -20.f : k4.z) * inv_temp);
    float ew = __expf((k4.w < 0.f ? -20.f : k4.w) * inv_temp);
    float s = ex + ey + ez + ew;
    // row lives in a 16-lane group; xor masks 1,2,4,8 stay in-group
    s += __shfl_xor(s, 1);
    s += __shfl_xor(s, 2);
    s += __shfl_xor(s, 4);
    s += __shfl_xor(s, 8);
    const float rs = __builtin_amdgcn_rcpf(s);
    ex *= rs; ey *= rs; ez *= rs; ew *= rs;
    ksk[0] += ex; ksk[1] += ey; ksk[2] += ez; ksk[3] += ew;

    *(float4*)&sk[w][rsub][equad] = make_float4(ex, ey, ez, ew);
    *(float4*)&sv[w][rsub][equad] = v4;
    lds_fence();

#pragma unroll
    for (int r = 0; r < 4; ++r) {
      const float4 ka0 = *(const float4*)&sk[w][r][d0];
      const float4 ka1 = *(const float4*)&sk[w][r][d0 + 4];
      const float4 va0 = *(const float4*)&sv[w][r][e0];
      const float4 va1 = *(const float4*)&sv[w][r][e0 + 4];
      const float ka[8] = {ka0.x, ka0.y, ka0.z, ka0.w, ka1.x, ka1.y, ka1.z, ka1.w};
      const float va[8] = {va0.x, va0.y, va0.z, va0.w, va1.x, va1.y, va1.z, va1.w};
#pragma unroll
      for (int i = 0; i < 8; ++i)
#pragma unroll
        for (int j = 0; j < 8; ++j)
          acc[i][j] = fmaf(ka[i], va[j], acc[i][j]);
    }
    k4 = nk4;
    v4 = nv4;
  }

  // Cross-wave KV reduction in LDS (the only barriers in this kernel).
#pragma unroll 1
  for (int pass = 0; pass < 4; ++pass) {
    if (w == pass) {
#pragma unroll
      for (int i = 0; i < 8; ++i) {
#pragma unroll
        for (int jq = 0; jq < 2; ++jq) {
          float4* p = (float4*)&red[(d0 + i) * 64 + e0 + jq * 4];
          float4 c = (pass == 0) ? make_float4(0.f, 0.f, 0.f, 0.f) : *p;
          c.x += acc[i][jq * 4 + 0];
          c.y += acc[i][jq * 4 + 1];
          c.z += acc[i][jq * 4 + 2];
          c.w += acc[i][jq * 4 + 3];
          *p = c;
        }
      }
    }
    __syncthreads();
  }

  float* kvdst = ws_kv + (size_t)bh * 4096;
#pragma unroll
  for (int rr = 0; rr < 16; ++rr)
    atomicAdd(&kvdst[rr * 256 + t], red[rr * 256 + t]);

  // ksum: fold the 4 row-groups together, then one atomic per column
  ksk[0] += __shfl_xor(ksk[0], 16); ksk[0] += __shfl_xor(ksk[0], 32);
  ksk[1] += __shfl_xor(ksk[1], 16); ksk[1] += __shfl_xor(ksk[1], 32);
  ksk[2] += __shfl_xor(ksk[2], 16); ksk[2] += __shfl_xor(ksk[2], 32);
  ksk[3] += __shfl_xor(ksk[3], 16); ksk[3] += __shfl_xor(ksk[3], 32);
  if (lane < 16) {
    atomicAdd(&ws_ksum[bh * 64 + equad + 0], ksk[0]);
    atomicAdd(&ws_ksum[bh * 64 + equad + 1], ksk[1]);
    atomicAdd(&ws_ksum[bh * 64 + equad + 2], ksk[2]);
    atomicAdd(&ws_ksum[bh * 64 + equad + 3], ksk[3]);
  }
}

// Phase 2: out[l][d] = sum_e w[l][e]*KV[e][d], w = Eq/(Eq.ksum + eps*sum(Eq)).
// sWT is wave-private (it always was) -> barriers replaced by lds_fence.
__global__ __launch_bounds__(256, 4) void p2_out(
    const float* __restrict__ Qp, const float* __restrict__ delta1,
    const float* __restrict__ ws_kv, const float* __restrict__ ws_ksum,
    float* __restrict__ outp) {
  const int t = threadIdx.x;
  const int bh = blockIdx.y;
  const int b = bh >> 4, h = bh & 15;
  const int lane = t & 63;
  const int w = t >> 6;
  const float inv_temp = inv_softplus_temp(delta1);
  const size_t base = ((size_t)b * L_DIM * H_DIM + h) * E_DIM;
  const int l0 = blockIdx.x * P2_CHUNK + w * (P2_CHUNK / 4);

  const int rsub = lane >> 4;
  const int equad = (lane & 15) << 2;

  // KV column for my output feature d=lane, all 64 contraction features
  float kvcol[64];
#pragma unroll
  for (int e = 0; e < 64; ++e)
    kvcol[e] = ws_kv[(size_t)bh * 4096 + e * 64 + lane];

  const float4 ks4 = *(const float4*)&ws_ksum[bh * 64 + equad];

  __shared__ float sWT[4][64][4];  // [wave][e][row-in-group] -- wave-private

  const int NIT = (P2_CHUNK / 4) / 4;  // 32 iterations of 4 rows per wave
  const float* qp = Qp + base + (size_t)(l0 + rsub) * ROWSTRIDE + equad;
  float* op0 = outp + base + (size_t)l0 * ROWSTRIDE + lane;

  float4 q4 = *(const float4*)qp;
  for (int it = 0; it < NIT; ++it) {
    const int pit = (it + 1 < NIT) ? it + 1 : it;
    const float4 nq4 = *(const float4*)(qp + (size_t)pit * (4 * ROWSTRIDE));

    float ex = __expf((q4.x < 0.f ? -20.f : q4.x) * inv_temp);
    float ey = __expf((q4.y < 0.f ? -20.f : q4.y) * inv_temp);
    float ez = __expf((q4.z < 0.f ? -20.f : q4.z) * inv_temp);
    float ew = __expf((q4.w < 0.f ? -20.f : q4.w) * inv_temp);
    float sE = ex + ey + ez + ew;
    float sD = ex * ks4.x + ey * ks4.y + ez * ks4.z + ew * ks4.w;
    sE += __shfl_xor(sE, 1); sD += __shfl_xor(sD, 1);
    sE += __shfl_xor(sE, 2); sD += __shfl_xor(sD, 2);
    sE += __shfl_xor(sE, 4); sD += __shfl_xor(sD, 4);
    sE += __shfl_xor(sE, 8); sD += __shfl_xor(sD, 8);
    // w = E / (E.ksum + eps*S)  ==  z * softmax(q) exactly (eps preserved)
    const float scale = __builtin_amdgcn_rcpf(sD + 1e-6f * sE);

    sWT[w][equad + 0][rsub] = ex * scale;
    sWT[w][equad + 1][rsub] = ey * scale;
    sWT[w][equad + 2][rsub] = ez * scale;
    sWT[w][equad + 3][rsub] = ew * scale;
    lds_fence();

    float a0 = 0.f, a1 = 0.f, a2 = 0.f, a3 = 0.f;
#pragma unroll
    for (int e = 0; e < 64; ++e) {
      const float4 wv = *(const float4*)&sWT[w][e][0];  // broadcast b128
      const float kve = kvcol[e];
      a0 = fmaf(wv.x, kve, a0);
      a1 = fmaf(wv.y, kve, a1);
      a2 = fmaf(wv.z, kve, a2);
      a3 = fmaf(wv.w, kve, a3);
    }

    float* op = op0 + (size_t)it * (4 * ROWSTRIDE);
    op[0] = a0;
    op[ROWSTRIDE] = a1;
    op[2 * (size_t)ROWSTRIDE] = a2;
    op[3 * (size_t)ROWSTRIDE] = a3;
    q4 = nq4;
  }
}

extern "C" void kernel_launch(void* const* d_in, const int* in_sizes, int n_in,
                              void* d_out, int out_size, void* d_ws, size_t ws_size,
                              hipStream_t stream) {
  (void)in_sizes; (void)n_in; (void)out_size; (void)ws_size;
  const float* Q = (const float*)d_in[0];
  const float* K = (const float*)d_in[1];
  const float* V = (const float*)d_in[2];
  const float* delta1 = (const float*)d_in[3];
  float* out = (float*)d_out;

  float* ws_kv = (float*)d_ws;                       // BH * 64 * 64
  float* ws_ksum = ws_kv + (size_t)BH * 4096;        // BH * 64
  const size_t zero_bytes = ((size_t)BH * 4096 + (size_t)BH * 64) * sizeof(float);
  hipMemsetAsync(d_ws, 0, zero_bytes, stream);

  dim3 blk(256);
  dim3 g1(L_DIM / P1_CHUNK, BH);
  p1_kv<<<g1, blk, 0, stream>>>(K, V, delta1, ws_kv, ws_ksum);
  dim3 g2(L_DIM / P2_CHUNK, BH);
  p2_out<<<g2, blk, 0, stream>>>(Q, delta1, ws_kv, ws_ksum, out);
}

// Round 2
// 512.719 us; speedup vs baseline: 1.3611x; 1.3611x over previous
//
#include <hip/hip_runtime.h>

#define L_DIM 4096
#define H_DIM 16
#define E_DIM 64
#define BH 128
#define ROWSTRIDE 1024  // H_DIM*E_DIM floats between consecutive l

#define P1_CHUNK 512
#define P2_CHUNK 256

__device__ __forceinline__ float inv_softplus_temp(const float* delta1) {
  // temp = softplus(delta1); return 1/temp
  return 1.0f / log1pf(__expf(delta1[0]));
}

__device__ __forceinline__ void lds_fence() {
  // Intra-wave LDS RAW visibility: DS ops issue in program order across the
  // wave; lgkmcnt(0) makes all lanes' preceding ds_writes visible to this
  // wave's subsequent ds_reads. No __syncthreads (LDS tiles are wave-private).
  asm volatile("s_waitcnt lgkmcnt(0)" ::: "memory");
}

// Phase 1: per (b,h): KV[d][e] = sum_l ktil[l][d]*v[l][e]; ksum[d] = sum_l ktil[l][d].
// Waves split the e-dimension (16 columns each) and ALL cover every row of the
// chunk. Softmax needs the full K row, so each wave loads/normalizes K
// redundantly (~6% extra VALU, loads hit L1). acc = 4x4 = 16 VGPR/lane.
// Zero barriers; each wave atomics its disjoint KV slice at the end.
__global__ __launch_bounds__(256) void p1_kv(
    const float* __restrict__ Kp, const float* __restrict__ Vp,
    const float* __restrict__ delta1,
    float* __restrict__ ws_kv, float* __restrict__ ws_ksum) {
  const int t = threadIdx.x;
  const int bh = blockIdx.y;
  const int b = bh >> 4, h = bh & 15;
  const int lane = t & 63;
  const int w = t >> 6;
  const float inv_temp = inv_softplus_temp(delta1);
  const size_t base = ((size_t)b * L_DIM * H_DIM + h) * E_DIM;
  const int l0 = blockIdx.x * P1_CHUNK;

  const int rsub = lane >> 4;          // 0..3: row within 4-row group
  const int equad = (lane & 15) << 2;  // K-load column quad (0,4,..,60)
  const int d0 = (lane >> 2) << 2;     // acc d-tile base: 0,4,...,60
  const int e0 = (lane & 3) << 2;      // acc e-tile base within slice: 0,4,8,12

  __shared__ float sk[4][4][64];  // [wave][row][d]  -- wave-private
  __shared__ float sv[4][4][16];  // [wave][row][e-slice]

  float acc[4][4];
#pragma unroll
  for (int i = 0; i < 4; ++i)
#pragma unroll
    for (int j = 0; j < 4; ++j) acc[i][j] = 0.f;
  float ksk[4] = {0.f, 0.f, 0.f, 0.f};

  const int NIT = P1_CHUNK / 4;  // 128 groups of 4 rows, every wave sees all
  const float* kp = Kp + base + (size_t)(l0 + rsub) * ROWSTRIDE + equad;
  const float* vp = Vp + base + (size_t)(l0 + rsub) * ROWSTRIDE + (w << 4) + (lane & 15);

  float4 k4 = *(const float4*)kp;
  float v1 = *vp;

  for (int it = 0; it < NIT; ++it) {
    // prefetch next 4-row group (clamped; last iter re-reads = L1 hit)
    const int pit = (it + 1 < NIT) ? it + 1 : it;
    const float4 nk4 = *(const float4*)(kp + (size_t)pit * (4 * ROWSTRIDE));
    const float nv1 = vp[(size_t)pit * (4 * ROWSTRIDE)];

    float ex = __expf((k4.x < 0.f ? -20.f : k4.x) * inv_temp);
    float ey = __expf((k4.y < 0.f ? -20.f : k4.y) * inv_temp);
    float ez = __expf((k4.z < 0.f ? -20.f : k4.z) * inv_temp);
    float ew = __expf((k4.w < 0.f ? -20.f : k4.w) * inv_temp);
    float s = ex + ey + ez + ew;
    // row lives in a 16-lane group; xor masks 1,2,4,8 stay in-group
    s += __shfl_xor(s, 1);
    s += __shfl_xor(s, 2);
    s += __shfl_xor(s, 4);
    s += __shfl_xor(s, 8);
    const float rs = __builtin_amdgcn_rcpf(s);
    ex *= rs; ey *= rs; ez *= rs; ew *= rs;
    if (w == 0) {  // every wave sees every row; count ksum exactly once
      ksk[0] += ex; ksk[1] += ey; ksk[2] += ez; ksk[3] += ew;
    }

    *(float4*)&sk[w][rsub][equad] = make_float4(ex, ey, ez, ew);
    sv[w][rsub][lane & 15] = v1;
    lds_fence();

#pragma unroll
    for (int r = 0; r < 4; ++r) {
      const float4 kt = *(const float4*)&sk[w][r][d0];
      const float4 vv = *(const float4*)&sv[w][r][e0];
      const float ka[4] = {kt.x, kt.y, kt.z, kt.w};
      const float va[4] = {vv.x, vv.y, vv.z, vv.w};
#pragma unroll
      for (int i = 0; i < 4; ++i)
#pragma unroll
        for (int j = 0; j < 4; ++j)
          acc[i][j] = fmaf(ka[i], va[j], acc[i][j]);
    }
    k4 = nk4;
    v1 = nv1;
  }

  // Each wave owns a disjoint 64x16 slice -> direct atomics, no block reduce.
  float* kvdst = ws_kv + (size_t)bh * 4096 + (w << 4);
#pragma unroll
  for (int i = 0; i < 4; ++i)
#pragma unroll
    for (int j = 0; j < 4; ++j)
      atomicAdd(&kvdst[(d0 + i) * 64 + e0 + j], acc[i][j]);

  if (w == 0) {
    // fold the 4 row-subgroups, then one atomic per column
    ksk[0] += __shfl_xor(ksk[0], 16); ksk[0] += __shfl_xor(ksk[0], 32);
    ksk[1] += __shfl_xor(ksk[1], 16); ksk[1] += __shfl_xor(ksk[1], 32);
    ksk[2] += __shfl_xor(ksk[2], 16); ksk[2] += __shfl_xor(ksk[2], 32);
    ksk[3] += __shfl_xor(ksk[3], 16); ksk[3] += __shfl_xor(ksk[3], 32);
    if (lane < 16) {
      atomicAdd(&ws_ksum[bh * 64 + equad + 0], ksk[0]);
      atomicAdd(&ws_ksum[bh * 64 + equad + 1], ksk[1]);
      atomicAdd(&ws_ksum[bh * 64 + equad + 2], ksk[2]);
      atomicAdd(&ws_ksum[bh * 64 + equad + 3], ksk[3]);
    }
  }
}

// Phase 2: out[l][d] = sum_e w[l][e]*KV[e][d], w = Eq/(Eq.ksum + eps*sum(Eq)).
// sWT is wave-private -> no barriers, lgkmcnt fence only. Plain launch bounds
// (kvcol[64] needs ~100 VGPR; the (256,4) hint made the backend spill it).
__global__ __launch_bounds__(256) void p2_out(
    const float* __restrict__ Qp, const float* __restrict__ delta1,
    const float* __restrict__ ws_kv, const float* __restrict__ ws_ksum,
    float* __restrict__ outp) {
  const int t = threadIdx.x;
  const int bh = blockIdx.y;
  const int b = bh >> 4, h = bh & 15;
  const int lane = t & 63;
  const int w = t >> 6;
  const float inv_temp = inv_softplus_temp(delta1);
  const size_t base = ((size_t)b * L_DIM * H_DIM + h) * E_DIM;
  const int l0 = blockIdx.x * P2_CHUNK + w * (P2_CHUNK / 4);

  const int rsub = lane >> 4;
  const int equad = (lane & 15) << 2;

  // KV column for my output feature d=lane, all 64 contraction features
  float kvcol[64];
#pragma unroll
  for (int e = 0; e < 64; ++e)
    kvcol[e] = ws_kv[(size_t)bh * 4096 + e * 64 + lane];

  const float4 ks4 = *(const float4*)&ws_ksum[bh * 64 + equad];

  __shared__ float sWT[4][64][4];  // [wave][e][row-in-group] -- wave-private

  const int NIT = (P2_CHUNK / 4) / 4;  // groups of 4 rows per wave
  const float* qp = Qp + base + (size_t)(l0 + rsub) * ROWSTRIDE + equad;
  float* op0 = outp + base + (size_t)l0 * ROWSTRIDE + lane;

  float4 q4 = *(const float4*)qp;
  for (int it = 0; it < NIT; ++it) {
    const int pit = (it + 1 < NIT) ? it + 1 : it;
    const float4 nq4 = *(const float4*)(qp + (size_t)pit * (4 * ROWSTRIDE));

    float ex = __expf((q4.x < 0.f ? -20.f : q4.x) * inv_temp);
    float ey = __expf((q4.y < 0.f ? -20.f : q4.y) * inv_temp);
    float ez = __expf((q4.z < 0.f ? -20.f : q4.z) * inv_temp);
    float ew = __expf((q4.w < 0.f ? -20.f : q4.w) * inv_temp);
    float sE = ex + ey + ez + ew;
    float sD = ex * ks4.x + ey * ks4.y + ez * ks4.z + ew * ks4.w;
    sE += __shfl_xor(sE, 1); sD += __shfl_xor(sD, 1);
    sE += __shfl_xor(sE, 2); sD += __shfl_xor(sD, 2);
    sE += __shfl_xor(sE, 4); sD += __shfl_xor(sD, 4);
    sE += __shfl_xor(sE, 8); sD += __shfl_xor(sD, 8);
    // w = E / (E.ksum + eps*S)  ==  z * softmax(q) exactly (eps preserved)
    const float scale = __builtin_amdgcn_rcpf(sD + 1e-6f * sE);

    sWT[w][equad + 0][rsub] = ex * scale;
    sWT[w][equad + 1][rsub] = ey * scale;
    sWT[w][equad + 2][rsub] = ez * scale;
    sWT[w][equad + 3][rsub] = ew * scale;
    lds_fence();

    float a0 = 0.f, a1 = 0.f, a2 = 0.f, a3 = 0.f;
#pragma unroll
    for (int e = 0; e < 64; ++e) {
      const float4 wv = *(const float4*)&sWT[w][e][0];  // same-addr broadcast b128
      const float kve = kvcol[e];
      a0 = fmaf(wv.x, kve, a0);
      a1 = fmaf(wv.y, kve, a1);
      a2 = fmaf(wv.z, kve, a2);
      a3 = fmaf(wv.w, kve, a3);
    }

    float* op = op0 + (size_t)it * (4 * ROWSTRIDE);
    op[0] = a0;
    op[ROWSTRIDE] = a1;
    op[2 * (size_t)ROWSTRIDE] = a2;
    op[3 * (size_t)ROWSTRIDE] = a3;
    q4 = nq4;
  }
}

extern "C" void kernel_launch(void* const* d_in, const int* in_sizes, int n_in,
                              void* d_out, int out_size, void* d_ws, size_t ws_size,
                              hipStream_t stream) {
  (void)in_sizes; (void)n_in; (void)out_size; (void)ws_size;
  const float* Q = (const float*)d_in[0];
  const float* K = (const float*)d_in[1];
  const float* V = (const float*)d_in[2];
  const float* delta1 = (const float*)d_in[3];
  float* out = (float*)d_out;

  float* ws_kv = (float*)d_ws;                       // BH * 64 * 64
  float* ws_ksum = ws_kv + (size_t)BH * 4096;        // BH * 64
  const size_t zero_bytes = ((size_t)BH * 4096 + (size_t)BH * 64) * sizeof(float);
  hipMemsetAsync(d_ws, 0, zero_bytes, stream);

  dim3 blk(256);
  dim3 g1(L_DIM / P1_CHUNK, BH);
  p1_kv<<<g1, blk, 0, stream>>>(K, V, delta1, ws_kv, ws_ksum);
  dim3 g2(L_DIM / P2_CHUNK, BH);
  p2_out<<<g2, blk, 0, stream>>>(Q, delta1, ws_kv, ws_ksum, out);
}

// Round 3
// 473.631 us; speedup vs baseline: 1.4734x; 1.0825x over previous
//
#include <hip/hip_runtime.h>

#define L_DIM 4096
#define H_DIM 16
#define E_DIM 64
#define BH 128
#define ROWSTRIDE 1024  // H_DIM*E_DIM floats between consecutive l

#define P1_CHUNK 512
#define P2_CHUNK 256

__device__ __forceinline__ float inv_softplus_temp(const float* delta1) {
  // temp = softplus(delta1); return 1/temp
  return 1.0f / log1pf(__expf(delta1[0]));
}

__device__ __forceinline__ void lds_fence() {
  // Intra-wave LDS RAW visibility: DS ops issue in program order across the
  // wave; lgkmcnt(0) makes all lanes' preceding ds_writes visible to this
  // wave's subsequent ds_reads. No __syncthreads (LDS tiles are wave-private).
  asm volatile("s_waitcnt lgkmcnt(0)" ::: "memory");
}

// Phase 1: per (b,h): KV[d][e] = sum_l ktil[l][d]*v[l][e]; ksum[d] = sum_l ktil[l][d].
// One wave = full 64x64 KV tile via an 8x8 register tile per lane
// (64 lanes x 8x8 = 4096). Each wave owns a disjoint 128-row span:
//   - exp/normalize computed exactly ONCE per row (no redundancy)
//   - LDS staging is wave-private (no barriers in the main loop)
//   - 8x8 tile -> 2 FLOP per LDS byte (VALU-balanced, was 1 with 4x4)
// Cross-wave merge once at block end (4 LDS passes + 4096 atomics/block).
// NOTE: plain __launch_bounds__(256). (256,4) made the allocator cap at 64
// VGPR and spill the accumulator to scratch (round-1 失败: +450MB HBM traffic).
__global__ __launch_bounds__(256) void p1_kv(
    const float* __restrict__ Kp, const float* __restrict__ Vp,
    const float* __restrict__ delta1,
    float* __restrict__ ws_kv, float* __restrict__ ws_ksum) {
  const int t = threadIdx.x;
  const int bh = blockIdx.y;
  const int b = bh >> 4, h = bh & 15;
  const int lane = t & 63;
  const int w = t >> 6;
  const float inv_temp = inv_softplus_temp(delta1);
  const size_t base = ((size_t)b * L_DIM * H_DIM + h) * E_DIM;
  const int l0 = blockIdx.x * P1_CHUNK + w * (P1_CHUNK / 4);  // wave's 128 rows

  const int rsub = lane >> 4;          // 0..3: row within 4-row group
  const int equad = (lane & 15) << 2;  // load column quad (0,4,..,60)
  const int d0 = (lane >> 3) << 3;     // 8-wide d-tile base: 0,8,...,56
  const int e0 = (lane & 7) << 3;      // 8-wide e-tile base: 0,8,...,56

  __shared__ float sk[4][4][64];  // [wave][row][d] -- wave-private
  __shared__ float sv[4][4][64];  // [wave][row][e]
  __shared__ float red[4096];     // cross-wave KV merge buffer

  float acc[8][8];
#pragma unroll
  for (int i = 0; i < 8; ++i)
#pragma unroll
    for (int j = 0; j < 8; ++j) acc[i][j] = 0.f;
  float ksk[4] = {0.f, 0.f, 0.f, 0.f};

  const int NIT = (P1_CHUNK / 4) / 4;  // 32 groups of 4 rows per wave
  const float* kp = Kp + base + (size_t)(l0 + rsub) * ROWSTRIDE + equad;
  const float* vp = Vp + base + (size_t)(l0 + rsub) * ROWSTRIDE + equad;

  float4 k4 = *(const float4*)kp;
  float4 v4 = *(const float4*)vp;

  for (int it = 0; it < NIT; ++it) {
    // prefetch next 4-row group (clamped; last iter re-reads = L1 hit)
    const int pit = (it + 1 < NIT) ? it + 1 : it;
    const float4 nk4 = *(const float4*)(kp + (size_t)pit * (4 * ROWSTRIDE));
    const float4 nv4 = *(const float4*)(vp + (size_t)pit * (4 * ROWSTRIDE));

    float ex = __expf((k4.x < 0.f ? -20.f : k4.x) * inv_temp);
    float ey = __expf((k4.y < 0.f ? -20.f : k4.y) * inv_temp);
    float ez = __expf((k4.z < 0.f ? -20.f : k4.z) * inv_temp);
    float ew = __expf((k4.w < 0.f ? -20.f : k4.w) * inv_temp);
    float s = ex + ey + ez + ew;
    // row lives in a 16-lane group; xor masks 1,2,4,8 stay in-group
    s += __shfl_xor(s, 1);
    s += __shfl_xor(s, 2);
    s += __shfl_xor(s, 4);
    s += __shfl_xor(s, 8);
    const float rs = __builtin_amdgcn_rcpf(s);
    ex *= rs; ey *= rs; ez *= rs; ew *= rs;
    ksk[0] += ex; ksk[1] += ey; ksk[2] += ez; ksk[3] += ew;  // own rows only

    *(float4*)&sk[w][rsub][equad] = make_float4(ex, ey, ez, ew);
    *(float4*)&sv[w][rsub][equad] = v4;
    lds_fence();

#pragma unroll
    for (int r = 0; r < 4; ++r) {
      const float4 ka0 = *(const float4*)&sk[w][r][d0];
      const float4 ka1 = *(const float4*)&sk[w][r][d0 + 4];
      const float4 va0 = *(const float4*)&sv[w][r][e0];
      const float4 va1 = *(const float4*)&sv[w][r][e0 + 4];
      const float ka[8] = {ka0.x, ka0.y, ka0.z, ka0.w, ka1.x, ka1.y, ka1.z, ka1.w};
      const float va[8] = {va0.x, va0.y, va0.z, va0.w, va1.x, va1.y, va1.z, va1.w};
#pragma unroll
      for (int i = 0; i < 8; ++i)
#pragma unroll
        for (int j = 0; j < 8; ++j)
          acc[i][j] = fmaf(ka[i], va[j], acc[i][j]);
    }
    k4 = nk4;
    v4 = nv4;
  }

  // Cross-wave KV merge in LDS (the only barriers in this kernel, once/block).
#pragma unroll 1
  for (int pass = 0; pass < 4; ++pass) {
    if (w == pass) {
#pragma unroll
      for (int i = 0; i < 8; ++i) {
#pragma unroll
        for (int jq = 0; jq < 2; ++jq) {
          float4* p = (float4*)&red[(d0 + i) * 64 + e0 + jq * 4];
          float4 c = (pass == 0) ? make_float4(0.f, 0.f, 0.f, 0.f) : *p;
          c.x += acc[i][jq * 4 + 0];
          c.y += acc[i][jq * 4 + 1];
          c.z += acc[i][jq * 4 + 2];
          c.w += acc[i][jq * 4 + 3];
          *p = c;
        }
      }
    }
    __syncthreads();
  }

  float* kvdst = ws_kv + (size_t)bh * 4096;
#pragma unroll
  for (int rr = 0; rr < 16; ++rr)
    atomicAdd(&kvdst[rr * 256 + t], red[rr * 256 + t]);

  // ksum: every wave owns distinct rows -> all waves contribute.
  // Fold the 4 row-subgroups (xor 16, 32), then one atomic per column.
  ksk[0] += __shfl_xor(ksk[0], 16); ksk[0] += __shfl_xor(ksk[0], 32);
  ksk[1] += __shfl_xor(ksk[1], 16); ksk[1] += __shfl_xor(ksk[1], 32);
  ksk[2] += __shfl_xor(ksk[2], 16); ksk[2] += __shfl_xor(ksk[2], 32);
  ksk[3] += __shfl_xor(ksk[3], 16); ksk[3] += __shfl_xor(ksk[3], 32);
  if (lane < 16) {
    atomicAdd(&ws_ksum[bh * 64 + equad + 0], ksk[0]);
    atomicAdd(&ws_ksum[bh * 64 + equad + 1], ksk[1]);
    atomicAdd(&ws_ksum[bh * 64 + equad + 2], ksk[2]);
    atomicAdd(&ws_ksum[bh * 64 + equad + 3], ksk[3]);
  }
}

// Phase 2: out[l][d] = sum_e w[l][e]*KV[e][d], w = Eq/(Eq.ksum + eps*sum(Eq)).
// sWT is wave-private -> no barriers, lgkmcnt fence only.
__global__ __launch_bounds__(256) void p2_out(
    const float* __restrict__ Qp, const float* __restrict__ delta1,
    const float* __restrict__ ws_kv, const float* __restrict__ ws_ksum,
    float* __restrict__ outp) {
  const int t = threadIdx.x;
  const int bh = blockIdx.y;
  const int b = bh >> 4, h = bh & 15;
  const int lane = t & 63;
  const int w = t >> 6;
  const float inv_temp = inv_softplus_temp(delta1);
  const size_t base = ((size_t)b * L_DIM * H_DIM + h) * E_DIM;
  const int l0 = blockIdx.x * P2_CHUNK + w * (P2_CHUNK / 4);

  const int rsub = lane >> 4;
  const int equad = (lane & 15) << 2;

  // KV column for my output feature d=lane, all 64 contraction features
  float kvcol[64];
#pragma unroll
  for (int e = 0; e < 64; ++e)
    kvcol[e] = ws_kv[(size_t)bh * 4096 + e * 64 + lane];

  const float4 ks4 = *(const float4*)&ws_ksum[bh * 64 + equad];

  __shared__ float sWT[4][64][4];  // [wave][e][row-in-group] -- wave-private

  const int NIT = (P2_CHUNK / 4) / 4;  // groups of 4 rows per wave
  const float* qp = Qp + base + (size_t)(l0 + rsub) * ROWSTRIDE + equad;
  float* op0 = outp + base + (size_t)l0 * ROWSTRIDE + lane;

  float4 q4 = *(const float4*)qp;
  for (int it = 0; it < NIT; ++it) {
    const int pit = (it + 1 < NIT) ? it + 1 : it;
    const float4 nq4 = *(const float4*)(qp + (size_t)pit * (4 * ROWSTRIDE));

    float ex = __expf((q4.x < 0.f ? -20.f : q4.x) * inv_temp);
    float ey = __expf((q4.y < 0.f ? -20.f : q4.y) * inv_temp);
    float ez = __expf((q4.z < 0.f ? -20.f : q4.z) * inv_temp);
    float ew = __expf((q4.w < 0.f ? -20.f : q4.w) * inv_temp);
    float sE = ex + ey + ez + ew;
    float sD = ex * ks4.x + ey * ks4.y + ez * ks4.z + ew * ks4.w;
    sE += __shfl_xor(sE, 1); sD += __shfl_xor(sD, 1);
    sE += __shfl_xor(sE, 2); sD += __shfl_xor(sD, 2);
    sE += __shfl_xor(sE, 4); sD += __shfl_xor(sD, 4);
    sE += __shfl_xor(sE, 8); sD += __shfl_xor(sD, 8);
    // w = E / (E.ksum + eps*S)  ==  z * softmax(q) exactly (eps preserved)
    const float scale = __builtin_amdgcn_rcpf(sD + 1e-6f * sE);

    sWT[w][equad + 0][rsub] = ex * scale;
    sWT[w][equad + 1][rsub] = ey * scale;
    sWT[w][equad + 2][rsub] = ez * scale;
    sWT[w][equad + 3][rsub] = ew * scale;
    lds_fence();

    float a0 = 0.f, a1 = 0.f, a2 = 0.f, a3 = 0.f;
#pragma unroll
    for (int e = 0; e < 64; ++e) {
      const float4 wv = *(const float4*)&sWT[w][e][0];  // same-addr broadcast b128
      const float kve = kvcol[e];
      a0 = fmaf(wv.x, kve, a0);
      a1 = fmaf(wv.y, kve, a1);
      a2 = fmaf(wv.z, kve, a2);
      a3 = fmaf(wv.w, kve, a3);
    }

    float* op = op0 + (size_t)it * (4 * ROWSTRIDE);
    op[0] = a0;
    op[ROWSTRIDE] = a1;
    op[2 * (size_t)ROWSTRIDE] = a2;
    op[3 * (size_t)ROWSTRIDE] = a3;
    q4 = nq4;
  }
}

extern "C" void kernel_launch(void* const* d_in, const int* in_sizes, int n_in,
                              void* d_out, int out_size, void* d_ws, size_t ws_size,
                              hipStream_t stream) {
  (void)in_sizes; (void)n_in; (void)out_size; (void)ws_size;
  const float* Q = (const float*)d_in[0];
  const float* K = (const float*)d_in[1];
  const float* V = (const float*)d_in[2];
  const float* delta1 = (const float*)d_in[3];
  float* out = (float*)d_out;

  float* ws_kv = (float*)d_ws;                       // BH * 64 * 64
  float* ws_ksum = ws_kv + (size_t)BH * 4096;        // BH * 64
  const size_t zero_bytes = ((size_t)BH * 4096 + (size_t)BH * 64) * sizeof(float);
  hipMemsetAsync(d_ws, 0, zero_bytes, stream);

  dim3 blk(256);
  dim3 g1(L_DIM / P1_CHUNK, BH);
  p1_kv<<<g1, blk, 0, stream>>>(K, V, delta1, ws_kv, ws_ksum);
  dim3 g2(L_DIM / P2_CHUNK, BH);
  p2_out<<<g2, blk, 0, stream>>>(Q, delta1, ws_kv, ws_ksum, out);
}